// Round 5
// baseline (393.745 us; speedup 1.0000x reference)
//
#include <hip/hip_runtime.h>
#include <hip/hip_bf16.h>
#include <stdint.h>

// Problem constants (B,T,C) = (4,4096,1024)
#define TT 4096
#define BB 4
#define CC 1024
#define MM (BB * TT)          // 16384 rows
#define NCHUNK 128            // scan chunks along T
#define CHUNK_T (TT / NCHUNK) // 32 steps per chunk
#define NCHAIN (BB * CC)      // 4096 independent scan chains

typedef float f32x4 __attribute__((ext_vector_type(4)));
typedef __bf16 bf16x8 __attribute__((ext_vector_type(8)));

__device__ __forceinline__ float b2f(ushort u) {
  union { float f; uint32_t v; } x; x.v = ((uint32_t)u) << 16; return x.f;
}
__device__ __forceinline__ ushort f2b(float f) { // RNE fp32->bf16
  union { float f; uint32_t u; } x; x.f = f;
  uint32_t r = x.u + 0x7fffu + ((x.u >> 16) & 1u);
  return (ushort)(r >> 16);
}

// async global->LDS, 16B per lane. LDS dest must be uniform-base + lane*16.
__device__ __forceinline__ void async_copy16(const ushort* g, ushort* l) {
  __builtin_amdgcn_global_load_lds(
      (__attribute__((address_space(1))) void*)(g),
      (__attribute__((address_space(3))) void*)(l), 16, 0, 0);
}

// One kernel converts x, Wf, Wg, Wp to bf16. Sizes in float4 units:
// x: 4194304, each W: 262144. Total 4980736 = 19456 * 256 exactly.
__global__ __launch_bounds__(256) void cvt_all(const float* __restrict__ x,
                                               const float* __restrict__ wf,
                                               const float* __restrict__ wg,
                                               const float* __restrict__ wp,
                                               ushort* __restrict__ xb,
                                               ushort* __restrict__ wcat,
                                               ushort* __restrict__ wpb) {
  const int i = blockIdx.x * 256 + threadIdx.x;
  const float* s; ushort* d; int off;
  if (i < 4194304)            { s = x;  d = xb;              off = i; }
  else if (i < 4456448)       { s = wf; d = wcat;            off = i - 4194304; }
  else if (i < 4718592)       { s = wg; d = wcat + 1048576;  off = i - 4456448; }
  else                        { s = wp; d = wpb;             off = i - 4718592; }
  float4 v = ((const float4*)s)[off];
  ushort4 o;
  o.x = f2b(v.x); o.y = f2b(v.y); o.z = f2b(v.z); o.w = f2b(v.w);
  ((ushort4*)d)[off] = o;
}

// ===== ROUND-5 STRUCTURE: weights-resident-in-LDS, barrier-free K-loop =====
// C[m][n] = sum_k A[m][k] * W[n][k], K=1024. Block = 256 rows (m) x 64 cols (n),
// full K via two k-halves; W half-slab (64 n x 512 k = 64 KB) lives in LDS,
// A is loaded DIRECTLY global->VGPR as MFMA fragments (16 B/lane contiguous).
// Only 4 barriers per block (around the two W-slab loads); 256 MFMA between
// barriers per wave. acc persists across halves.
// Block map: mg = b & 63 (m-part, 256 rows), ns = b >> 6 (n-slab). xcd = b%8 =
// mg%8 -> all 32 same-m blocks on one XCD; per-XCD A footprint = 8 parts x
// 0.5 MB = 4 MB = L2 size -> A re-reads are L2-local.
// W LDS swizzle: row r (1 KB = 64 slots x 16B) stores global octet g at slot
// g ^ (r&7); reader slot = (s*4+kq) ^ (r&7) -> 2 lanes/bank-group = free.
// Operand-swapped MFMA (R3-verified): mfma(w_frag, a_frag) -> n on reg axis.
// MODE 0: f32x4 stores. MODE 1: sigmoid (ns<16) / tanh, ushort4 stores.
template <int MODE, int N>
__global__ __launch_bounds__(256) void gemm_ws(const ushort* __restrict__ A,
                                               const ushort* __restrict__ Bw,
                                               float* __restrict__ outF,
                                               ushort* __restrict__ outB) {
  constexpr int K = CC;
  __shared__ __align__(16) ushort sW[64 * 512]; // 64 KB
  const int tid = threadIdx.x;
  const int lane = tid & 63;
  const int w = tid >> 6;            // wave -> m quarter of the block
  const int b = blockIdx.x;
  const int mg = b & 63;
  const int ns = b >> 6;
  const long n0 = (long)ns * 64;
  const long mbase = (long)mg * 256 + (long)w * 64;
  const int rlo = lane & 15;
  const int kq = lane >> 4;

  f32x4 acc[4][4];
#pragma unroll
  for (int i = 0; i < 4; ++i)
#pragma unroll
    for (int j = 0; j < 4; ++j) acc[i][j] = (f32x4){0.f, 0.f, 0.f, 0.f};

  // Per-lane A row bases (4 m-frags)
  const ushort* arow[4];
#pragma unroll
  for (int i = 0; i < 4; ++i) arow[i] = A + (mbase + i * 16 + rlo) * K + kq * 8;

  for (int kh = 0; kh < 2; ++kh) {
    if (kh) __syncthreads(); // all waves done reading half-0 before overwrite
    // stage W half: wave w loads rows c = w*16 .. w*16+15 (1 KB each)
#pragma unroll
    for (int t = 0; t < 16; ++t) {
      const int c = w * 16 + t;
      const int g = lane ^ (c & 7); // fetch octet that lands at slot=lane
      async_copy16(Bw + (n0 + c) * K + kh * 512 + g * 8, &sW[c * 512 + lane * 8]);
    }
    __syncthreads();

#pragma unroll 4
    for (int s = 0; s < 16; ++s) {
      const long kof = (long)kh * 512 + s * 32;
      bf16x8 af[4], bfr[4];
#pragma unroll
      for (int i = 0; i < 4; ++i)
        af[i] = *(const bf16x8*)(arow[i] + kof);
#pragma unroll
      for (int j = 0; j < 4; ++j) {
        const int r = j * 16 + rlo;
        const int slot = (s * 4 + kq) ^ (r & 7);
        bfr[j] = *(const bf16x8*)&sW[r * 512 + slot * 8];
      }
#pragma unroll
      for (int i = 0; i < 4; ++i)
#pragma unroll
        for (int j = 0; j < 4; ++j)
          acc[i][j] = __builtin_amdgcn_mfma_f32_16x16x32_bf16(bfr[j], af[i], acc[i][j], 0, 0, 0);
    }
  }

  // Swapped C/D mapping (R3-verified): m = lane&15 axis, n = (lane>>4)*4 + reg.
  const int mloc = lane & 15;
  const int rq = lane >> 4;
#pragma unroll
  for (int i = 0; i < 4; ++i) {
    const long m = mbase + i * 16 + mloc;
#pragma unroll
    for (int j = 0; j < 4; ++j) {
      const long nb = n0 + j * 16 + rq * 4; // 4 consecutive n
      const f32x4 v = acc[i][j];
      if (MODE == 0) {
        *(f32x4*)(outF + m * N + nb) = v;
      } else {
        float act[4];
        if (n0 < CC) { // sigmoid region (block-uniform; 64 | 1024)
#pragma unroll
          for (int r = 0; r < 4; ++r)
            act[r] = __builtin_amdgcn_rcpf(1.f + __expf(-v[r]));
        } else {       // tanh = 1 - 2/(exp(2v)+1)
#pragma unroll
          for (int r = 0; r < 4; ++r)
            act[r] = fmaf(-2.f, __builtin_amdgcn_rcpf(1.f + __expf(2.f * v[r])), 1.f);
        }
        ushort4 o;
        o.x = f2b(act[0]); o.y = f2b(act[1]); o.z = f2b(act[2]); o.w = f2b(act[3]);
        *(ushort4*)(outB + m * (long)N + nb) = o;
      }
    }
  }
}

// P layout: [m=b*T+t][0..1023]=f (bf16), [1024..2047]=g (bf16)
// Recurrence h_t = f*h + (1-f)*g. Four chains per thread (ushort4 loads).
__global__ __launch_bounds__(256) void scan_pass1(const ushort* __restrict__ P,
                                                  float* __restrict__ cA,
                                                  float* __restrict__ cB) {
  const int pc = blockIdx.x * 256 + threadIdx.x; // chain quad 0..1023
  const int chunk = blockIdx.y;
  const int b = pc >> 8, c4 = (pc & 255) * 4;
  const ushort4* p =
      (const ushort4*)(P + (size_t)(b * TT + chunk * CHUNK_T) * (2 * CC) + c4);
  float A[4] = {1.f, 1.f, 1.f, 1.f};
  float h[4] = {0.f, 0.f, 0.f, 0.f};
#pragma unroll 4
  for (int i = 0; i < CHUNK_T; ++i) {
    const ushort4 fu = p[0];
    const ushort4 gu = p[CC / 4];
    p += 2 * CC / 4;
    const float f[4] = {b2f(fu.x), b2f(fu.y), b2f(fu.z), b2f(fu.w)};
    const float g[4] = {b2f(gu.x), b2f(gu.y), b2f(gu.z), b2f(gu.w)};
#pragma unroll
    for (int r = 0; r < 4; ++r) {
      A[r] *= f[r];
      h[r] = fmaf(f[r], h[r], (1.f - f[r]) * g[r]);
    }
  }
  const int ci = chunk * NCHAIN + b * CC + c4;
  *(f32x4*)(cA + ci) = (f32x4){A[0], A[1], A[2], A[3]};
  *(f32x4*)(cB + ci) = (f32x4){h[0], h[1], h[2], h[3]};
}

// Carry computed inline (scan over prior chunks' cA/cB), then fixup + write H.
__global__ __launch_bounds__(256) void scan_pass3(const ushort* __restrict__ P,
                                                  const float* __restrict__ cA,
                                                  const float* __restrict__ cB,
                                                  ushort* __restrict__ H) {
  const int pc = blockIdx.x * 256 + threadIdx.x;
  const int chunk = blockIdx.y;
  const int b = pc >> 8, c4 = (pc & 255) * 4;
  const int ci = b * CC + c4;
  float h[4] = {0.f, 0.f, 0.f, 0.f};
  for (int j = 0; j < chunk; ++j) {
    const f32x4 a = *(const f32x4*)(cA + j * NCHAIN + ci);
    const f32x4 bb = *(const f32x4*)(cB + j * NCHAIN + ci);
#pragma unroll
    for (int r = 0; r < 4; ++r) h[r] = fmaf(a[r], h[r], bb[r]);
  }
  const ushort4* p =
      (const ushort4*)(P + (size_t)(b * TT + chunk * CHUNK_T) * (2 * CC) + c4);
  ushort4* hp = (ushort4*)(H + (size_t)(b * TT + chunk * CHUNK_T) * CC + c4);
#pragma unroll 4
  for (int i = 0; i < CHUNK_T; ++i) {
    const ushort4 fu = p[0];
    const ushort4 gu = p[CC / 4];
    p += 2 * CC / 4;
    const float f[4] = {b2f(fu.x), b2f(fu.y), b2f(fu.z), b2f(fu.w)};
    const float g[4] = {b2f(gu.x), b2f(gu.y), b2f(gu.z), b2f(gu.w)};
    ushort4 o;
#pragma unroll
    for (int r = 0; r < 4; ++r)
      h[r] = fmaf(f[r], h[r], (1.f - f[r]) * g[r]);
    o.x = f2b(h[0]); o.y = f2b(h[1]); o.z = f2b(h[2]); o.w = f2b(h[3]);
    *hp = o;
    hp += CC / 4;
  }
}

extern "C" void kernel_launch(void* const* d_in, const int* in_sizes, int n_in,
                              void* d_out, int out_size, void* d_ws, size_t ws_size,
                              hipStream_t stream) {
  const float* x  = (const float*)d_in[0];
  const float* Wf = (const float*)d_in[1];
  const float* Wg = (const float*)d_in[2];
  const float* Wp = (const float*)d_in[3];

  // workspace layout (bytes); H aliases xb (xb dead after gates GEMM, stream-ordered)
  char* ws = (char*)d_ws;
  ushort* xb   = (ushort*)(ws);                                  // 33554432 B
  ushort* Hb   = xb;                                             // alias
  ushort* Wcat = (ushort*)(ws + 33554432);                       //  4194304 B (Wf||Wg)
  ushort* Wpb  = (ushort*)(ws + 33554432 + 4194304);             //  2097152 B
  ushort* P    = (ushort*)(ws + 33554432 + 4194304 + 2097152);   // 67108864 B (f||g bf16)
  char* tail   = ws + 33554432 + 4194304 + 2097152 + 67108864;
  float* cA    = (float*)(tail);                                 // 2 MiB (128*4096*4)
  float* cB    = (float*)(tail + 2097152);                       // 2 MiB
  (void)ws_size; (void)in_sizes; (void)n_in; (void)out_size;

  // 1) all fp32 -> bf16 conversions in one launch
  cvt_all<<<19456, 256, 0, stream>>>(x, Wf, Wg, Wp, xb, Wcat, Wpb);

  // 2) gates GEMM: [16384 x 2048] = xb @ Wcat^T, fused sigmoid/tanh -> P (bf16)
  //    64 m-parts x 32 n-slabs = 2048 blocks
  gemm_ws<1, 2 * CC><<<2048, 256, 0, stream>>>(xb, Wcat, nullptr, P);

  // 3) chunked scan: pass1 per-chunk compose, pass3 inline-carry + fixup
  dim3 gs(NCHAIN / 4 / 256, NCHUNK);
  scan_pass1<<<gs, 256, 0, stream>>>(P, cA, cB);
  scan_pass3<<<gs, 256, 0, stream>>>(P, cA, cB, Hb);

  // 4) projection GEMM: out = H @ Wp^T (fp32): 64 m-parts x 16 n-slabs = 1024 blocks
  gemm_ws<0, CC><<<1024, 256, 0, stream>>>(Hb, Wpb, (float*)d_out, nullptr);
}

// Round 6
// 288.668 us; speedup vs baseline: 1.3640x; 1.3640x over previous
//
#include <hip/hip_runtime.h>
#include <hip/hip_bf16.h>
#include <stdint.h>

// Problem constants (B,T,C) = (4,4096,1024)
#define TT 4096
#define BB 4
#define CC 1024
#define MM (BB * TT)          // 16384 rows
#define NCHUNK 64             // scan chunks along T
#define CHUNK_T (TT / NCHUNK) // 64 steps per chunk
#define NCHAIN (BB * CC)      // 4096 independent scan chains

typedef float f32x4 __attribute__((ext_vector_type(4)));
typedef __bf16 bf16x8 __attribute__((ext_vector_type(8)));

__device__ __forceinline__ float b2f(ushort u) {
  union { float f; uint32_t v; } x; x.v = ((uint32_t)u) << 16; return x.f;
}
__device__ __forceinline__ ushort f2b(float f) { // RNE fp32->bf16
  union { float f; uint32_t u; } x; x.f = f;
  uint32_t r = x.u + 0x7fffu + ((x.u >> 16) & 1u);
  return (ushort)(r >> 16);
}

// async global->LDS, 16B per lane. LDS dest must be uniform-base + lane*16.
__device__ __forceinline__ void async_copy16(const ushort* g, ushort* l) {
  __builtin_amdgcn_global_load_lds(
      (__attribute__((address_space(1))) void*)(g),
      (__attribute__((address_space(3))) void*)(l), 16, 0, 0);
}

// One kernel converts x, Wf, Wg, Wp to bf16. Sizes in float4 units:
// x: 4194304, each W: 262144. Total 4980736 = 19456 * 256 exactly.
__global__ __launch_bounds__(256) void cvt_all(const float* __restrict__ x,
                                               const float* __restrict__ wf,
                                               const float* __restrict__ wg,
                                               const float* __restrict__ wp,
                                               ushort* __restrict__ xb,
                                               ushort* __restrict__ wcat,
                                               ushort* __restrict__ wpb) {
  const int i = blockIdx.x * 256 + threadIdx.x;
  const float* s; ushort* d; int off;
  if (i < 4194304)            { s = x;  d = xb;              off = i; }
  else if (i < 4456448)       { s = wf; d = wcat;            off = i - 4194304; }
  else if (i < 4718592)       { s = wg; d = wcat + 1048576;  off = i - 4456448; }
  else                        { s = wp; d = wpb;             off = i - 4718592; }
  float4 v = ((const float4*)s)[off];
  ushort4 o;
  o.x = f2b(v.x); o.y = f2b(v.y); o.z = f2b(v.z); o.w = f2b(v.w);
  ((ushort4*)d)[off] = o;
}

// C[m][n] = sum_k A[m][k] * Bw[n][k]  (row-major, K=1024 contiguous).
// ROUND-6: 128x128 tile, 4 waves 2x2 (R3-proven internals), BK=64 ->
// 16 staging-wait slots per block instead of 32 (same total bytes, 32 KB LDS,
// still ~3 blocks/CU by VGPR). Evidence R1-R5: duration tracks wait-slot
// count, not per-iteration internals.
// LDS layout: row stride 64 bf16 (128 B); octet o (16 B) of row r stored at
// slot o ^ (r&7)  -> staging writes are lane-linear (async-copy compatible)
// and fragment reads hit each bank pair exactly twice (2-way = free, m136).
// Operand-swapped MFMA (R3): n on reg axis -> packed 4-wide stores.
// MODE 0: f32x4 stores. MODE 1: sigmoid (n<1024) / tanh (n>=1024), ushort4.
template <int MODE>
__global__ __launch_bounds__(256) void gemm_bt(const ushort* __restrict__ A,
                                               const ushort* __restrict__ Bw,
                                               float* __restrict__ outF,
                                               ushort* __restrict__ outB, int N) {
  constexpr int K = CC;
  __shared__ __align__(16) ushort sA[128 * 64]; // 16 KB
  __shared__ __align__(16) ushort sB[128 * 64]; // 16 KB
  const int tid = threadIdx.x;
  const int lane = tid & 63;
  const int wid = tid >> 6;
  const int wm = wid >> 1, wn = wid & 1;
  const long m0 = (long)blockIdx.y * 128;
  const long n0 = (long)blockIdx.x * 128;

  f32x4 acc[4][4];
#pragma unroll
  for (int i = 0; i < 4; ++i)
#pragma unroll
    for (int j = 0; j < 4; ++j) acc[i][j] = (f32x4){0.f, 0.f, 0.f, 0.f};

  // staging: one wave-chunk = 8 rows x 64 bf16 (1 KB). lane -> row = lane>>3,
  // writes LDS slot lane&7; fetches global octet (lane&7) ^ (row&7).
  const int srow8 = lane >> 3;
  const int g8 = (lane & 7) ^ (srow8 & 7);
  const ushort* Ab = A + (m0 + srow8) * K + g8 * 8;
  const ushort* Bb = Bw + (n0 + srow8) * K + g8 * 8;
  // fragment read: slot = octet ^ (row&7); row&7 == rlo&7 (i*16, w*64 are 0 mod 8)
  const int kq = lane >> 4;
  const int rlo = lane & 15;
  const int rx = rlo & 7;

  for (int k0 = 0; k0 < K; k0 += 64) {
    // 32 chunks of 8 rows: A = 0..15, B = 16..31; 8 per wave
#pragma unroll
    for (int ch = wid; ch < 32; ch += 4) {
      if (ch < 16)
        async_copy16(Ab + (long)(ch * 8) * K + k0, &sA[ch * 512 + lane * 8]);
      else
        async_copy16(Bb + (long)((ch - 16) * 8) * K + k0, &sB[(ch - 16) * 512 + lane * 8]);
    }
    __syncthreads();

#pragma unroll
    for (int s = 0; s < 2; ++s) {
      const int slot = (s * 4 + kq) ^ rx;
      bf16x8 af[4], bfr[4];
#pragma unroll
      for (int i = 0; i < 4; ++i) {
        af[i]  = *(const bf16x8*)&sA[(wm * 64 + i * 16 + rlo) * 64 + slot * 8];
        bfr[i] = *(const bf16x8*)&sB[(wn * 64 + i * 16 + rlo) * 64 + slot * 8];
      }
#pragma unroll
      for (int i = 0; i < 4; ++i)
#pragma unroll
        for (int j = 0; j < 4; ++j)
          acc[i][j] = __builtin_amdgcn_mfma_f32_16x16x32_bf16(bfr[j], af[i], acc[i][j], 0, 0, 0);
    }
    __syncthreads();
  }

  // Swapped C/D mapping (R3-verified): m = lane&15 axis, n = (lane>>4)*4 + reg.
  const int mloc = lane & 15;
  const int rq = lane >> 4;
#pragma unroll
  for (int i = 0; i < 4; ++i) {
    const long m = m0 + wm * 64 + i * 16 + mloc;
#pragma unroll
    for (int j = 0; j < 4; ++j) {
      const long nb = n0 + wn * 64 + j * 16 + rq * 4; // 4 consecutive n
      const f32x4 v = acc[i][j];
      if (MODE == 0) {
        *(f32x4*)(outF + m * N + nb) = v;
      } else {
        float act[4];
        if (n0 < CC) { // sigmoid region (block-uniform; 128 | 1024)
#pragma unroll
          for (int r = 0; r < 4; ++r)
            act[r] = __builtin_amdgcn_rcpf(1.f + __expf(-v[r]));
        } else {       // tanh = 1 - 2/(exp(2v)+1)
#pragma unroll
          for (int r = 0; r < 4; ++r)
            act[r] = fmaf(-2.f, __builtin_amdgcn_rcpf(1.f + __expf(2.f * v[r])), 1.f);
        }
        ushort4 o;
        o.x = f2b(act[0]); o.y = f2b(act[1]); o.z = f2b(act[2]); o.w = f2b(act[3]);
        *(ushort4*)(outB + m * (long)N + nb) = o;
      }
    }
  }
}

// ===== Scan: R1-style 3-pass (cheapest measured), vectorized 4 chains/thread =====
// P layout: [m=b*T+t][0..1023]=f (bf16), [1024..2047]=g (bf16)
__global__ __launch_bounds__(256) void scan_pass1(const ushort* __restrict__ P,
                                                  float* __restrict__ cA,
                                                  float* __restrict__ cB) {
  const int pc = blockIdx.x * 256 + threadIdx.x; // chain quad 0..1023
  const int chunk = blockIdx.y;
  const int b = pc >> 8, c4 = (pc & 255) * 4;
  const ushort4* p =
      (const ushort4*)(P + (size_t)(b * TT + chunk * CHUNK_T) * (2 * CC) + c4);
  float A[4] = {1.f, 1.f, 1.f, 1.f};
  float h[4] = {0.f, 0.f, 0.f, 0.f};
#pragma unroll 4
  for (int i = 0; i < CHUNK_T; ++i) {
    const ushort4 fu = p[0];
    const ushort4 gu = p[CC / 4];
    p += 2 * CC / 4;
    const float f[4] = {b2f(fu.x), b2f(fu.y), b2f(fu.z), b2f(fu.w)};
    const float g[4] = {b2f(gu.x), b2f(gu.y), b2f(gu.z), b2f(gu.w)};
#pragma unroll
    for (int r = 0; r < 4; ++r) {
      A[r] *= f[r];
      h[r] = fmaf(f[r], h[r], (1.f - f[r]) * g[r]);
    }
  }
  const int ci = chunk * NCHAIN + b * CC + c4;
  *(f32x4*)(cA + ci) = (f32x4){A[0], A[1], A[2], A[3]};
  *(f32x4*)(cB + ci) = (f32x4){h[0], h[1], h[2], h[3]};
}

__global__ __launch_bounds__(256) void scan_pass2(const float* __restrict__ cA,
                                                  const float* __restrict__ cB,
                                                  float* __restrict__ hinit) {
  const int chain = blockIdx.x * 256 + threadIdx.x; // 0..4095
  float h = 0.f;
  for (int j = 0; j < NCHUNK; ++j) {
    hinit[j * NCHAIN + chain] = h; // exclusive carry
    h = fmaf(cA[j * NCHAIN + chain], h, cB[j * NCHAIN + chain]);
  }
}

__global__ __launch_bounds__(256) void scan_pass3(const ushort* __restrict__ P,
                                                  const float* __restrict__ hinit,
                                                  ushort* __restrict__ H) {
  const int pc = blockIdx.x * 256 + threadIdx.x;
  const int chunk = blockIdx.y;
  const int b = pc >> 8, c4 = (pc & 255) * 4;
  f32x4 hv = *(const f32x4*)(hinit + chunk * NCHAIN + b * CC + c4);
  float h[4] = {hv[0], hv[1], hv[2], hv[3]};
  const ushort4* p =
      (const ushort4*)(P + (size_t)(b * TT + chunk * CHUNK_T) * (2 * CC) + c4);
  ushort4* hp = (ushort4*)(H + (size_t)(b * TT + chunk * CHUNK_T) * CC + c4);
#pragma unroll 4
  for (int i = 0; i < CHUNK_T; ++i) {
    const ushort4 fu = p[0];
    const ushort4 gu = p[CC / 4];
    p += 2 * CC / 4;
    const float f[4] = {b2f(fu.x), b2f(fu.y), b2f(fu.z), b2f(fu.w)};
    const float g[4] = {b2f(gu.x), b2f(gu.y), b2f(gu.z), b2f(gu.w)};
    ushort4 o;
#pragma unroll
    for (int r = 0; r < 4; ++r)
      h[r] = fmaf(f[r], h[r], (1.f - f[r]) * g[r]);
    o.x = f2b(h[0]); o.y = f2b(h[1]); o.z = f2b(h[2]); o.w = f2b(h[3]);
    *hp = o;
    hp += CC / 4;
  }
}

extern "C" void kernel_launch(void* const* d_in, const int* in_sizes, int n_in,
                              void* d_out, int out_size, void* d_ws, size_t ws_size,
                              hipStream_t stream) {
  const float* x  = (const float*)d_in[0];
  const float* Wf = (const float*)d_in[1];
  const float* Wg = (const float*)d_in[2];
  const float* Wp = (const float*)d_in[3];

  // workspace layout (bytes); H aliases xb (xb dead after gates GEMM, stream-ordered)
  char* ws = (char*)d_ws;
  ushort* xb   = (ushort*)(ws);                                  // 33554432 B
  ushort* Hb   = xb;                                             // alias
  ushort* Wcat = (ushort*)(ws + 33554432);                       //  4194304 B (Wf||Wg)
  ushort* Wpb  = (ushort*)(ws + 33554432 + 4194304);             //  2097152 B
  ushort* P    = (ushort*)(ws + 33554432 + 4194304 + 2097152);   // 67108864 B (f||g bf16)
  char* tail   = ws + 33554432 + 4194304 + 2097152 + 67108864;
  float* cA    = (float*)(tail);                                 // 1 MiB (64*4096*4)
  float* cB    = (float*)(tail + 1048576);                       // 1 MiB
  float* hinit = (float*)(tail + 2097152);                       // 1 MiB
  (void)ws_size; (void)in_sizes; (void)n_in; (void)out_size;

  // 1) all fp32 -> bf16 conversions in one launch
  cvt_all<<<19456, 256, 0, stream>>>(x, Wf, Wg, Wp, xb, Wcat, Wpb);

  // 2) gates GEMM: [16384 x 2048] = xb @ Wcat^T, fused sigmoid/tanh -> P (bf16)
  dim3 g1(2 * CC / 128, MM / 128); // 16 x 128 = 2048 blocks
  gemm_bt<1><<<g1, 256, 0, stream>>>(xb, Wcat, nullptr, P, 2 * CC);

  // 3) chunked scan: 3-pass (per-chunk compose, carry scan, fixup)
  dim3 gs(NCHAIN / 4 / 256, NCHUNK);
  scan_pass1<<<gs, 256, 0, stream>>>(P, cA, cB);
  scan_pass2<<<NCHAIN / 256, 256, 0, stream>>>(cA, cB, hinit);
  scan_pass3<<<gs, 256, 0, stream>>>(P, hinit, Hb);

  // 4) projection GEMM: out = H @ Wp^T (fp32), 128x128 tile
  dim3 g3(CC / 128, MM / 128); // 8 x 128 = 1024 blocks
  gemm_bt<0><<<g3, 256, 0, stream>>>(Hb, Wpb, (float*)d_out, nullptr, CC);
}